// Round 6
// baseline (347.160 us; speedup 1.0000x reference)
//
#include <hip/hip_runtime.h>
#include <hip/hip_bf16.h>

// GravNetConv: N=16384, C_IN=128, S=4, P=32, K=16, C_OUT=128.
// Mask-free path: [k1] proj (fp64 s) -> [k2t] threshold via radix-ladder histogram ->
// [k1b] pack bf16x2-split MFMA operands with threshold folded into K-slots ->
// [k2sel] fused N^2 Gram (mfma_f32_32x32x16_bf16) + per-lane bit decode + exact-d2
// top-16 in registers (u64 keys, top_k-stable); writes 4 partial top-16/query ->
// [k3m] 4-way merge + aggregation -> [k4a/k4_out2] out = x@W1^T + agg@W2^T + b2.
// Fallback path (ws_size < 41MB): round-2 kernels.

#define NPTS 16384
#define CIN  128
#define SD   4
#define PD   32
#define KNN  16
#define COUT 128
#define FLTMAX 3.4028234663852886e+38f
#define NBIN 33
#define EPAD 1e-3f  // mask-inclusion pad >> bf16x2 Gram error bound (~2e-4)

typedef float v2f __attribute__((ext_vector_type(2)));
typedef unsigned int uint;
typedef unsigned long long u64;
typedef unsigned short u16;
typedef __attribute__((ext_vector_type(8))) short bf16x8;
typedef __attribute__((ext_vector_type(16))) float f32x16;

// ---- shared offsets (both paths) ----
#define WS_S4     0            // N * float4 = 256 KB
#define WS_H      0x40000      // N * 32 f32 = 2 MB
// ---- mask-free path offsets ----
#define WS_AGG_M  0x280000     // [N][64] f32 = 4 MB (written by k3m, after k2sel)
#define WS_SA     0x280000     // aliases AGG: N*16 bf16 = 512 KB, dead before k3m
#define WS_SB     0x300000     // aliases AGG: N*16 bf16 = 512 KB, dead before k3m
#define WS_WT_M   0x680000     // [192][128] f32 = 96 KB
#define WS_T2     0x6A0000     // N f32 = 64 KB
#define WS_PW     0x700000     // 64 * N * u64 = 8 MB (partial top-16 keys)
#define WS_NEED_M 0x2700000    // 40.9 MB gate (unchanged)
// ---- fallback offsets ----
#define WS_CJ_F   0x400000
#define WS_AGG_F  0xC00000
#define WS_WT_F   0x1000000
#define JS   16
#define TJF  (NPTS/JS)

__device__ __forceinline__ float d2f(const float4 a, const float4 b) {
  v2f d0 = {a.x - b.x, a.y - b.y};
  v2f d1 = {a.z - b.z, a.w - b.w};
  v2f pr = d0*d0 + d1*d1;
  return pr.x + pr.y;
}

__device__ __forceinline__ u16 f2bf(float x) {   // RNE float->bf16
  uint u = __float_as_uint(x);
  uint r = (u + 0x7FFFu + ((u >> 16) & 1u)) >> 16;
  return (u16)r;
}
__device__ __forceinline__ float bf2f(u16 h) {
  return __uint_as_float(((uint)h) << 16);
}

// ---------------- Kernel 1: s (fp64 accumulate) and h projections ----------------
__global__ __launch_bounds__(256) void k1_proj(
    const float* __restrict__ x, const float* __restrict__ Ws, const float* __restrict__ bs,
    const float* __restrict__ Wh, const float* __restrict__ bh,
    float4* __restrict__ s4, float* __restrict__ h) {
  __shared__ float  lw[36*128];
  __shared__ float  lx[64*132];
  __shared__ double rs[3*64*5];
  __shared__ float  rh[3*64*33];
  const int t = threadIdx.x;
  const int row0 = blockIdx.x * 64;
  for (int i2 = t; i2 < 36*128; i2 += 256)
    lw[i2] = (i2 < 512) ? Ws[i2] : Wh[i2 - 512];
#pragma unroll
  for (int g = 0; g < 8; ++g) {
    int fi = g*256 + t;
    int r = fi >> 5, c4 = fi & 31;
    *(float4*)&lx[r*132 + c4*4] = *(const float4*)&x[(size_t)(row0 + r)*CIN + c4*4];
  }
  __syncthreads();
  const int kq = t >> 6;
  const int r  = t & 63;
  const int kb = kq * 32;
  double sacc[4] = {0.0, 0.0, 0.0, 0.0};
  float  hacc[32];
#pragma unroll
  for (int p = 0; p < 32; ++p) hacc[p] = 0.f;
#pragma unroll
  for (int k4 = 0; k4 < 8; ++k4) {
    float4 xv = *(const float4*)&lx[r*132 + kb + k4*4];
    int kg = kb + k4*4;
#pragma unroll
    for (int p = 0; p < 4; ++p) {
      float4 wv = *(const float4*)&lw[p*128 + kg];
      sacc[p] = fma((double)xv.x, (double)wv.x, sacc[p]);
      sacc[p] = fma((double)xv.y, (double)wv.y, sacc[p]);
      sacc[p] = fma((double)xv.z, (double)wv.z, sacc[p]);
      sacc[p] = fma((double)xv.w, (double)wv.w, sacc[p]);
    }
#pragma unroll
    for (int p = 0; p < 32; ++p) {
      float4 wv = *(const float4*)&lw[(4+p)*128 + kg];
      hacc[p] = fmaf(xv.x, wv.x, fmaf(xv.y, wv.y, fmaf(xv.z, wv.z, fmaf(xv.w, wv.w, hacc[p]))));
    }
  }
  if (kq > 0) {
    const int bq = kq - 1;
#pragma unroll
    for (int d = 0; d < 4; ++d) rs[(bq*64 + r)*5 + d] = sacc[d];
#pragma unroll
    for (int p = 0; p < 32; ++p) rh[(bq*64 + r)*33 + p] = hacc[p];
  }
  __syncthreads();
  if (kq == 0) {
    const int row = row0 + r;
    float so[4];
#pragma unroll
    for (int d = 0; d < 4; ++d) {
      double sd = sacc[d] + rs[(0*64 + r)*5 + d] + rs[(1*64 + r)*5 + d]
                + rs[(2*64 + r)*5 + d] + (double)bs[d];
      so[d] = (float)sd;
    }
    s4[row] = make_float4(so[0], so[1], so[2], so[3]);
#pragma unroll
    for (int p4 = 0; p4 < 8; ++p4) {
      float o[4];
#pragma unroll
      for (int c = 0; c < 4; ++c) {
        int p = p4*4 + c;
        o[c] = hacc[p] + rh[(0*64 + r)*33 + p] + rh[(1*64 + r)*33 + p]
             + rh[(2*64 + r)*33 + p] + bh[p];
      }
      *(float4*)&h[(size_t)row*PD + p4*4] = make_float4(o[0], o[1], o[2], o[3]);
    }
  }
}

// ---------------- Kernel 2t: per-query threshold via radix-ladder histogram ----------------
__global__ __launch_bounds__(256) void k2t_thresh(
    const float4* __restrict__ s4, float* __restrict__ t2) {
  __shared__ float4 tile[2064];
  __shared__ uint   lhist[256*NBIN];
  const int t = threadIdx.x;
#pragma unroll
  for (int g = 0; g < 8; ++g) {
    int j = g*256 + t;
    tile[j + (j >> 7)] = s4[j];
  }
#pragma unroll
  for (int b = 0; b < NBIN; ++b) lhist[t*NBIN + b] = 0u;
  const int ql = t >> 4, tq = t & 15;
  const int q  = blockIdx.x*16 + ql;
  const float4 sq = s4[q];
  __syncthreads();
  float tau = d2f(sq, tile[tq*129]);
#pragma unroll
  for (int m = 1; m < 16; m <<= 1) tau = fmaxf(tau, __shfl_xor(tau, m, 16));
  const int ktop = (int)(__float_as_uint(tau) >> 21);
  const int hb = t*NBIN;
#pragma unroll 4
  for (int u = 0; u < 128; ++u) {
    float4 p = tile[tq*129 + u];
    float e = d2f(sq, p);
    int key = (int)(__float_as_uint(e) >> 21);
    int rel = ktop - key;
    rel = rel < 0 ? 0 : (rel > 32 ? 32 : rel);
    atomicAdd(&lhist[hb + rel], 1u);
  }
  __syncthreads();
  uint c0 = 0, c1 = 0;
  const int qb = ql*16;
  for (int u = 0; u < 16; ++u) {
    c0 += lhist[(qb + u)*NBIN + tq*2];
    c1 += (tq*2 + 1 < NBIN) ? lhist[(qb + u)*NBIN + tq*2 + 1] : 0u;
  }
  int S = (int)(c0 + c1);
#pragma unroll
  for (int d = 1; d < 16; d <<= 1) {
    int v = __shfl_down(S, d, 16);
    S += (tq + d < 16) ? v : 0;
  }
  int g = -1;
  if (S >= KNN) g = 2*tq;
  if (S - (int)c0 >= KNN) g = 2*tq + 1;
#pragma unroll
  for (int m = 1; m < 16; m <<= 1) g = max(g, __shfl_xor(g, m, 16));
  if (tq == 0) {
    uint K = (uint)(ktop - g);
    t2[q] = __uint_as_float((K << 21) | 0x1FFFFFu);
  }
}

// ---------------- Kernel 1b: pack MFMA operand rows (bf16x2 split + fold) -----------
// K-slot layout (16 slots):
//   sA row q (B operand): [hq(4) | hq(4) | lq(4) | 1, 1, aqh, aql]  aq = -(nq-t2q)/2 + EPAD
//   sB row j (A operand): [hj(4) | lj(4) | hj(4) | bnh, bnl, 1, 1]  bn = -nj/2
// dot_k = hj.hq + lj.hq + hj.lq + bn + aq = s_q.s_j (to ~2e-4) - nj/2 - (nq-t2q)/2 + EPAD
// predicate acc >= 0 is d2 <= t2q + 2*EPAD (superset of exact mask; exact re-rank follows).
__global__ __launch_bounds__(256) void k1b_pack(
    const float4* __restrict__ s4, const float* __restrict__ t2,
    uint4* __restrict__ sA, uint4* __restrict__ sB) {
  const int i = blockIdx.x*256 + threadIdx.x;
  const float4 s = s4[i];
  float sv[4] = {s.x, s.y, s.z, s.w};
  const float n2 = s.x*s.x + s.y*s.y + s.z*s.z + s.w*s.w;
  u16 hb[4], lb[4];
#pragma unroll
  for (int d = 0; d < 4; ++d) {
    u16 hh = f2bf(sv[d]);
    hb[d] = hh;
    lb[d] = f2bf(sv[d] - bf2f(hh));
  }
  const float aq = -0.5f*(n2 - t2[i]) + EPAD;
  const float bn = -0.5f*n2;
  u16 aqh = f2bf(aq); u16 aql = f2bf(aq - bf2f(aqh));
  u16 bnh = f2bf(bn); u16 bnl = f2bf(bn - bf2f(bnh));
  const uint oneone = 0x3F803F80u;
  uint a0 = (uint)hb[0] | ((uint)hb[1] << 16);
  uint a1 = (uint)hb[2] | ((uint)hb[3] << 16);
  uint l0 = (uint)lb[0] | ((uint)lb[1] << 16);
  uint l1 = (uint)lb[2] | ((uint)lb[3] << 16);
  uint aqw = (uint)aqh | ((uint)aql << 16);
  uint bnw = (uint)bnh | ((uint)bnl << 16);
  uint4 A0; A0.x = a0; A0.y = a1; A0.z = a0; A0.w = a1;
  uint4 A1; A1.x = l0; A1.y = l1; A1.z = oneone; A1.w = aqw;
  uint4 B0; B0.x = a0; B0.y = a1; B0.z = l0; B0.w = l1;
  uint4 B1; B1.x = a0; B1.y = a1; B1.z = bnw; B1.w = oneone;
  sA[(size_t)i*2]     = A0;
  sA[(size_t)i*2 + 1] = A1;
  sB[(size_t)i*2]     = B0;
  sB[(size_t)i*2 + 1] = B1;
}

// per-lane pack of 16 predicate bits from a 32x32 MFMA accumulator.
// bit for acc[i] goes to position (i&3) + 8*(i>>2) + shft (shft = 4*hi).
__device__ __forceinline__ uint packbits16(const f32x16 a, const int shft) {
  uint b[4];
#pragma unroll
  for (int g = 0; g < 4; ++g) {
    uint bg = 0u;
#pragma unroll
    for (int e = 3; e >= 0; --e)
      bg = bg + bg + ((~__float_as_uint(a[4*g + e])) >> 31);
    b[g] = bg;
  }
  return (b[0] | (b[1] << 8) | (b[2] << 16) | (b[3] << 24)) << shft;
}

// ---------------- Kernel 2sel: fused Gram + decode + exact top-16 -------------------
// Block: 128 threads = 2 waves; wave wv owns queries [qg*128+wv*64, +64).
// Block covers j-quarter jq (4096 j = 4 chunks of 1024 staged in LDS: bf16 ops +
// exact fp32 s4). Per 128-j group: 8 MFMAs -> per-lane predicate words (lane ln owns
// query qwb+ln after shfl_xor(32) merge) -> ctz decode -> exact d2 from LDS ->
// u64-key top-16 in registers (strict <, key=(d2bits<<14)|j: top_k-stable).
// Output: pw[(jq*16+r)*NPTS + q], coalesced.
__global__ __launch_bounds__(128) void k2sel(
    const u16* __restrict__ sA, const u16* __restrict__ sB,
    const float4* __restrict__ s4, u64* __restrict__ pw) {
  __shared__ u16    lB[1024*16];   // 32 KB bf16 operand rows
  __shared__ float4 ls4[1024];     // 16 KB exact fp32 rows
  const int t   = threadIdx.x;
  const int wv  = t >> 6, ln = t & 63;
  const int l31 = ln & 31, hi = ln >> 5;
  const int qg  = blockIdx.x >> 2, jq = blockIdx.x & 3;
  const int qwb = qg*128 + wv*64;
  const int j0  = jq*4096;
  const int q   = qwb + ln;
  const float4 sq = s4[q];
  const bf16x8 qf0 = *(const bf16x8*)&sA[(size_t)(qwb + l31)*16 + hi*8];
  const bf16x8 qf1 = *(const bf16x8*)&sA[(size_t)(qwb + 32 + l31)*16 + hi*8];
  u64 kv[16];
#pragma unroll
  for (int r = 0; r < 16; ++r) kv[r] = ~0ull;
  u64 cmx = ~0ull; int cpos = 0;
  const int sh = hi * 4;
  const f32x16 zc = {0.f,0.f,0.f,0.f,0.f,0.f,0.f,0.f,0.f,0.f,0.f,0.f,0.f,0.f,0.f,0.f};
#pragma unroll 1
  for (int cc = 0; cc < 4; ++cc) {
    __syncthreads();
    for (int r = t; r < 1024; r += 128) {
      const uint4* src = (const uint4*)&sB[(size_t)(j0 + cc*1024 + r)*16];
      uint4 v0 = src[0], v1 = src[1];
      *(uint4*)&lB[r*16]     = v0;
      *(uint4*)&lB[r*16 + 8] = v1;
      ls4[r] = s4[j0 + cc*1024 + r];
    }
    __syncthreads();
#pragma unroll 1
    for (int c8 = 0; c8 < 8; ++c8) {
      uint w0[4], w1[4];
#pragma unroll
      for (int jt = 0; jt < 4; ++jt) {
        const bf16x8 af = *(const bf16x8*)&lB[(c8*128 + jt*32 + l31)*16 + hi*8];
        f32x16 a0 = __builtin_amdgcn_mfma_f32_32x32x16_bf16(af, qf0, zc, 0, 0, 0);
        f32x16 a1 = __builtin_amdgcn_mfma_f32_32x32x16_bf16(af, qf1, zc, 0, 0, 0);
        w0[jt] = packbits16(a0, sh);
        w1[jt] = packbits16(a1, sh);
      }
#pragma unroll
      for (int jt = 0; jt < 4; ++jt) {
        uint f0 = w0[jt] | (uint)__shfl_xor((int)w0[jt], 32);
        uint f1 = w1[jt] | (uint)__shfl_xor((int)w1[jt], 32);
        uint bits = hi ? f1 : f0;
        while (bits) {
          int b = __builtin_ctz(bits); bits &= bits - 1;
          const int jl = c8*128 + jt*32 + b;
          float4 p = ls4[jl];
          float e = d2f(sq, p);
          u64 key = ((u64)__float_as_uint(e) << 14) | (uint)(j0 + cc*1024 + jl);
          if (key < cmx) {
#pragma unroll
            for (int r16 = 0; r16 < 16; ++r16) if (r16 == cpos) kv[r16] = key;
            cmx = kv[0]; cpos = 0;
#pragma unroll
            for (int r16 = 1; r16 < 16; ++r16) { if (kv[r16] > cmx) { cmx = kv[r16]; cpos = r16; } }
          }
        }
      }
    }
  }
#pragma unroll
  for (int r = 0; r < 16; ++r)
    pw[(size_t)(jq*16 + r)*NPTS + q] = kv[r];
}

// ---------------- Kernel 3m: 4-way merge of partial top-16s + aggregation ------------
// Block: 256 threads, 64 queries. (il,tq) loads partial entries c=tq*16+u into LDS
// (c-ascending slots -> stable merge order); t<64 merges 64 -> top-16 (u64 strict <);
// aggregation epilogue as in the proven fallback k3_merge_fb.
__global__ __launch_bounds__(256) void k3m(
    const u64* __restrict__ pw, const float4* __restrict__ h4, float* __restrict__ agg) {
  __shared__ u64   lk[64*65];    // 33.3 KB
  __shared__ float le[64*17];
  __shared__ int   lj[64*17];
  const int t  = threadIdx.x;
  const int il = t & 63, tq = t >> 6;
  const int i  = blockIdx.x*64 + il;
#pragma unroll
  for (int u = 0; u < 16; ++u) {
    const int c = tq*16 + u;
    lk[il*65 + c] = pw[(size_t)c*NPTS + i];
  }
  __syncthreads();
  if (t < 64) {
    u64 kv[16];
#pragma unroll
    for (int r = 0; r < 16; ++r) kv[r] = ~0ull;
    u64 cmx = ~0ull; int cpos = 0;
    for (int u = 0; u < 64; ++u) {
      u64 key = lk[t*65 + u];
      if (key < cmx) {
#pragma unroll
        for (int r16 = 0; r16 < 16; ++r16) if (r16 == cpos) kv[r16] = key;
        cmx = kv[0]; cpos = 0;
#pragma unroll
        for (int r16 = 1; r16 < 16; ++r16) { if (kv[r16] > cmx) { cmx = kv[r16]; cpos = r16; } }
      }
    }
#pragma unroll
    for (int r = 0; r < 16; ++r) {
      float d2v = __uint_as_float((uint)(kv[r] >> 14));
      le[t*17 + r] = __expf(-10.f * d2v);
      lj[t*17 + r] = (int)(kv[r] & 16383u);
    }
  }
  __syncthreads();
  float ms[8], mm[8];
#pragma unroll
  for (int p = 0; p < 8; ++p) { ms[p] = 0.f; mm[p] = -FLTMAX; }
#pragma unroll 1
  for (int r = 0; r < KNN; ++r) {
    float w = le[il*17 + r];
    int   j = lj[il*17 + r];
    float4 a = h4[(size_t)j*8 + tq*2];
    float4 b = h4[(size_t)j*8 + tq*2 + 1];
    float m0 = a.x*w, m1 = a.y*w, m2 = a.z*w, m3 = a.w*w;
    float m4 = b.x*w, m5 = b.y*w, m6 = b.z*w, m7 = b.w*w;
    ms[0] += m0; mm[0] = fmaxf(mm[0], m0);
    ms[1] += m1; mm[1] = fmaxf(mm[1], m1);
    ms[2] += m2; mm[2] = fmaxf(mm[2], m2);
    ms[3] += m3; mm[3] = fmaxf(mm[3], m3);
    ms[4] += m4; mm[4] = fmaxf(mm[4], m4);
    ms[5] += m5; mm[5] = fmaxf(mm[5], m5);
    ms[6] += m6; mm[6] = fmaxf(mm[6], m6);
    ms[7] += m7; mm[7] = fmaxf(mm[7], m7);
  }
  float4 o0 = make_float4(ms[0]*0.0625f, ms[1]*0.0625f, ms[2]*0.0625f, ms[3]*0.0625f);
  float4 o1 = make_float4(ms[4]*0.0625f, ms[5]*0.0625f, ms[6]*0.0625f, ms[7]*0.0625f);
  *(float4*)&agg[(size_t)i*64 + tq*8]      = o0;
  *(float4*)&agg[(size_t)i*64 + tq*8 + 4]  = o1;
  *(float4*)&agg[(size_t)i*64 + 32 + tq*8]     = make_float4(mm[0], mm[1], mm[2], mm[3]);
  *(float4*)&agg[(size_t)i*64 + 32 + tq*8 + 4] = make_float4(mm[4], mm[5], mm[6], mm[7]);
}

// ================= Fallback path (round-2, proven) =================
__global__ __launch_bounds__(256) void k2_knn_fb(
    const float4* __restrict__ s4, unsigned short* __restrict__ cand_j) {
  __shared__ float4 tile[TJF];
  __shared__ int    lbuf[256*33];
  const int t  = threadIdx.x;
  const int ib = blockIdx.x & 31;
  const int jc = blockIdx.x >> 5;
  const int jbase = jc * TJF;
#pragma unroll
  for (int g = 0; g < 4; ++g) tile[g*256 + t] = s4[jbase + g*256 + t];
  const int ia = ib*256 + t;
  const int ic = ia + 8192;
  const float4 sa = s4[ia];
  const float4 sc = s4[ic];
  __syncthreads();
  float va[KNN], vb[KNN]; int ja[KNN], jb[KNN];
#pragma unroll
  for (int q = 0; q < KNN; ++q) { va[q] = FLTMAX; ja[q] = 0; vb[q] = FLTMAX; jb[q] = 0; }
  float cma = FLTMAX, cmb = FLTMAX;
  int cpa = 0, cpb = 0, ca = 0, cb = 0;
  auto insertA = [&](float e, int jj) {
#pragma unroll
    for (int q = 0; q < KNN; ++q) if (q == cpa) { va[q] = e; ja[q] = jj; }
    cma = va[0]; cpa = 0;
#pragma unroll
    for (int q = 1; q < KNN; ++q) { if (va[q] > cma) { cma = va[q]; cpa = q; } }
  };
  auto insertB = [&](float e, int jj) {
#pragma unroll
    for (int q = 0; q < KNN; ++q) if (q == cpb) { vb[q] = e; jb[q] = jj; }
    cmb = vb[0]; cpb = 0;
#pragma unroll
    for (int q = 1; q < KNN; ++q) { if (vb[q] > cmb) { cmb = vb[q]; cpb = q; } }
  };
  auto compactA = [&]() {
    for (int u = 0; u < ca; ++u) {
      int jj = lbuf[t*33 + u];
      float e = d2f(sa, tile[jj]);
      if (e < cma) insertA(e, jj);
    }
    ca = 0;
  };
  auto compactB = [&]() {
    for (int u = 0; u < cb; ++u) {
      int jj = lbuf[t*33 + 16 + u];
      float e = d2f(sc, tile[jj]);
      if (e < cmb) insertB(e, jj);
    }
    cb = 0;
  };
  for (int ob = 0; ob < TJF/8; ++ob) {
#pragma unroll
    for (int u = 0; u < 8; ++u) {
      int jj = ob*8 + u;
      float4 p = tile[jj];
      float ea = d2f(sa, p);
      float eb = d2f(sc, p);
      if (ea < cma) { lbuf[t*33 + ca] = jj; ++ca; }
      if (eb < cmb) { lbuf[t*33 + 16 + cb] = jj; ++cb; }
    }
    if (__any(ca > 8)) compactA();
    if (__any(cb > 8)) compactB();
  }
  compactA(); compactB();
#pragma unroll
  for (int q = 0; q < KNN; ++q) {
    int c = jc*KNN + q;
    cand_j[(size_t)c*NPTS + ia] = (unsigned short)(ja[q] + jbase);
    cand_j[(size_t)c*NPTS + ic] = (unsigned short)(jb[q] + jbase);
  }
}

__global__ __launch_bounds__(256) void k3_merge_fb(
    const float4* __restrict__ s4, const float4* __restrict__ h4,
    const unsigned short* __restrict__ cand_j, float* __restrict__ agg) {
  __shared__ float le[64*67];
  __shared__ int   lj[64*67];
  const int t  = threadIdx.x;
  const int il = t & 63, tq = t >> 6;
  const int i  = blockIdx.x*64 + il;
  const float4 si = s4[i];
  float val[KNN]; int vid[KNN];
#pragma unroll
  for (int q = 0; q < KNN; ++q) { val[q] = FLTMAX; vid[q] = 0; }
  float cmax = FLTMAX; int cpos = 0;
  for (int u = 0; u < 64; ++u) {
    int c = tq*64 + u;
    int j = cand_j[(size_t)c*NPTS + i];
    float e = d2f(si, s4[j]);
    if (e < cmax) {
#pragma unroll
      for (int q = 0; q < KNN; ++q) if (q == cpos) { val[q] = e; vid[q] = j; }
      cmax = val[0]; cpos = 0;
#pragma unroll
      for (int q = 1; q < KNN; ++q) { if (val[q] > cmax) { cmax = val[q]; cpos = q; } }
    }
  }
#pragma unroll
  for (int q = 0; q < KNN; ++q) {
    le[il*67 + tq*16 + q] = val[q];
    lj[il*67 + tq*16 + q] = vid[q];
  }
  __syncthreads();
  if (t < 64) {
    float mv[KNN]; int mj[KNN];
#pragma unroll
    for (int q = 0; q < KNN; ++q) { mv[q] = FLTMAX; mj[q] = 0; }
    float cm2 = FLTMAX; int cp2 = 0;
    for (int u = 0; u < 64; ++u) {
      float e = le[t*67 + u];
      int   j = lj[t*67 + u];
      if (e < cm2) {
#pragma unroll
        for (int q = 0; q < KNN; ++q) if (q == cp2) { mv[q] = e; mj[q] = j; }
        cm2 = mv[0]; cp2 = 0;
#pragma unroll
        for (int q = 1; q < KNN; ++q) { if (mv[q] > cm2) { cm2 = mv[q]; cp2 = q; } }
      }
    }
#pragma unroll
    for (int q = 0; q < KNN; ++q) {
      le[t*67 + q] = __expf(-10.f * mv[q]);
      lj[t*67 + q] = mj[q];
    }
  }
  __syncthreads();
  float ms[8], mm[8];
#pragma unroll
  for (int p = 0; p < 8; ++p) { ms[p] = 0.f; mm[p] = -FLTMAX; }
#pragma unroll 1
  for (int q = 0; q < KNN; ++q) {
    float w = le[il*67 + q];
    int   j = lj[il*67 + q];
    float4 a = h4[(size_t)j*8 + tq*2];
    float4 b = h4[(size_t)j*8 + tq*2 + 1];
    float m0 = a.x*w, m1 = a.y*w, m2 = a.z*w, m3 = a.w*w;
    float m4 = b.x*w, m5 = b.y*w, m6 = b.z*w, m7 = b.w*w;
    ms[0] += m0; mm[0] = fmaxf(mm[0], m0);
    ms[1] += m1; mm[1] = fmaxf(mm[1], m1);
    ms[2] += m2; mm[2] = fmaxf(mm[2], m2);
    ms[3] += m3; mm[3] = fmaxf(mm[3], m3);
    ms[4] += m4; mm[4] = fmaxf(mm[4], m4);
    ms[5] += m5; mm[5] = fmaxf(mm[5], m5);
    ms[6] += m6; mm[6] = fmaxf(mm[6], m6);
    ms[7] += m7; mm[7] = fmaxf(mm[7], m7);
  }
  float4 o0 = make_float4(ms[0]*0.0625f, ms[1]*0.0625f, ms[2]*0.0625f, ms[3]*0.0625f);
  float4 o1 = make_float4(ms[4]*0.0625f, ms[5]*0.0625f, ms[6]*0.0625f, ms[7]*0.0625f);
  *(float4*)&agg[(size_t)i*64 + tq*8]      = o0;
  *(float4*)&agg[(size_t)i*64 + tq*8 + 4]  = o1;
  *(float4*)&agg[(size_t)i*64 + 32 + tq*8]     = make_float4(mm[0], mm[1], mm[2], mm[3]);
  *(float4*)&agg[(size_t)i*64 + 32 + tq*8 + 4] = make_float4(mm[4], mm[5], mm[6], mm[7]);
}

// ---------------- Kernel 4a: pack/transpose weights ----------------
__global__ __launch_bounds__(256) void k4a_wt(
    const float* __restrict__ W1, const float* __restrict__ W2, float* __restrict__ wT) {
  int idx = blockIdx.x*256 + threadIdx.x;
  if (idx >= 192*COUT) return;
  int k = idx >> 7, c = idx & 127;
  float v = (k < 128) ? W1[(size_t)c*128 + k] : W2[(size_t)c*64 + (k - 128)];
  wT[(size_t)k*COUT + c] = v;
}

// ---------------- Kernel 4: out = x@W1^T + agg@W2^T + b2 (32x128 tile, 4x4/thread) ----------
__global__ __launch_bounds__(256) void k4_out2(
    const float* __restrict__ x, const float* __restrict__ agg,
    const float* __restrict__ wT, const float* __restrict__ b2,
    float* __restrict__ out) {
  __shared__ float xa[32*192];
  const int t = threadIdx.x;
  const int row0 = blockIdx.x * 32;
#pragma unroll
  for (int g = 0; g < 4; ++g) {
    int fi = g*256 + t;
    int r = fi >> 5, c4 = fi & 31;
    *(float4*)&xa[r*192 + c4*4] = *(const float4*)&x[(size_t)(row0+r)*CIN + c4*4];
  }
#pragma unroll
  for (int g = 0; g < 2; ++g) {
    int fi = g*256 + t;
    int r = fi >> 4, c4 = fi & 15;
    *(float4*)&xa[r*192 + 128 + c4*4] = *(const float4*)&agg[(size_t)(row0+r)*64 + c4*4];
  }
  __syncthreads();
  const int c4 = t & 31;
  const int rg = t >> 5;
  float acc[4][4];
#pragma unroll
  for (int r = 0; r < 4; ++r) { acc[r][0]=0.f; acc[r][1]=0.f; acc[r][2]=0.f; acc[r][3]=0.f; }
  for (int k = 0; k < 192; k += 4) {
    float4 w0 = *(const float4*)&wT[(size_t)(k+0)*COUT + c4*4];
    float4 w1 = *(const float4*)&wT[(size_t)(k+1)*COUT + c4*4];
    float4 w2 = *(const float4*)&wT[(size_t)(k+2)*COUT + c4*4];
    float4 w3 = *(const float4*)&wT[(size_t)(k+3)*COUT + c4*4];
#pragma unroll
    for (int r = 0; r < 4; ++r) {
      float4 xv = *(const float4*)&xa[(rg*4 + r)*192 + k];
      acc[r][0] = fmaf(xv.x, w0.x, fmaf(xv.y, w1.x, fmaf(xv.z, w2.x, fmaf(xv.w, w3.x, acc[r][0]))));
      acc[r][1] = fmaf(xv.x, w0.y, fmaf(xv.y, w1.y, fmaf(xv.z, w2.y, fmaf(xv.w, w3.y, acc[r][1]))));
      acc[r][2] = fmaf(xv.x, w0.z, fmaf(xv.y, w1.z, fmaf(xv.z, w2.z, fmaf(xv.w, w3.z, acc[r][2]))));
      acc[r][3] = fmaf(xv.x, w0.w, fmaf(xv.y, w1.w, fmaf(xv.z, w2.w, fmaf(xv.w, w3.w, acc[r][3]))));
    }
  }
  float4 bias = *(const float4*)&b2[c4*4];
#pragma unroll
  for (int r = 0; r < 4; ++r) {
    float4 o = make_float4(acc[r][0]+bias.x, acc[r][1]+bias.y, acc[r][2]+bias.z, acc[r][3]+bias.w);
    *(float4*)&out[(size_t)(row0 + rg*4 + r)*COUT + c4*4] = o;
  }
}

extern "C" void kernel_launch(void* const* d_in, const int* in_sizes, int n_in,
                              void* d_out, int out_size, void* d_ws, size_t ws_size,
                              hipStream_t stream) {
  const float* x  = (const float*)d_in[0];
  const float* Ws = (const float*)d_in[1];
  const float* bs = (const float*)d_in[2];
  const float* Wh = (const float*)d_in[3];
  const float* bh = (const float*)d_in[4];
  const float* W1 = (const float*)d_in[5];
  const float* W2 = (const float*)d_in[6];
  const float* b2 = (const float*)d_in[7];
  float* out = (float*)d_out;

  char* ws = (char*)d_ws;
  float4* s4 = (float4*)(ws + WS_S4);
  float*  h  = (float*) (ws + WS_H);

  k1_proj<<<NPTS/64, 256, 0, stream>>>(x, Ws, bs, Wh, bh, s4, h);

  if (ws_size >= (size_t)WS_NEED_M) {
    float* t2  = (float*)(ws + WS_T2);
    float* agg = (float*)(ws + WS_AGG_M);
    float* wT  = (float*)(ws + WS_WT_M);
    uint4* sa  = (uint4*)(ws + WS_SA);
    uint4* sb  = (uint4*)(ws + WS_SB);
    u64*   pw  = (u64*)  (ws + WS_PW);
    k2t_thresh<<<NPTS/16, 256, 0, stream>>>(s4, t2);
    k1b_pack<<<NPTS/256, 256, 0, stream>>>(s4, t2, sa, sb);
    k2sel<<<512, 128, 0, stream>>>((const u16*)sa, (const u16*)sb, s4, pw);
    k3m<<<NPTS/64, 256, 0, stream>>>(pw, (const float4*)h, agg);
    k4a_wt<<<(192*COUT + 255)/256, 256, 0, stream>>>(W1, W2, wT);
    k4_out2<<<NPTS/32, 256, 0, stream>>>(x, agg, wT, b2, out);
  } else {
    unsigned short* cj = (unsigned short*)(ws + WS_CJ_F);
    float* agg = (float*)(ws + WS_AGG_F);
    float* wT  = (float*)(ws + WS_WT_F);
    k2_knn_fb<<<512, 256, 0, stream>>>(s4, cj);
    k3_merge_fb<<<NPTS/64, 256, 0, stream>>>(s4, (const float4*)h, cj, agg);
    k4a_wt<<<(192*COUT + 255)/256, 256, 0, stream>>>(W1, W2, wT);
    k4_out2<<<NPTS/32, 256, 0, stream>>>(x, agg, wT, b2, out);
  }
}